// Round 6
// baseline (516.696 us; speedup 1.0000x reference)
//
#include <hip/hip_runtime.h>

#define NJ 24
#define HIDN 7
#define FEATN 6

// R6 = R5 kernel, UNCHANGED, launched twice (idempotent) to measure the
// kernel's true dispatch time: dur2 - dur1(R5) = K exactly.
__global__ __launch_bounds__(256)
void structure_encoder_kernel(const float* __restrict__ x,
                              const float* __restrict__ W1,
                              const float* __restrict__ b1,
                              const float* __restrict__ W2,
                              const float* __restrict__ b2,
                              float* __restrict__ out, int B)
{
    __shared__ float4 obuf[4][64 * 13];   // 53248 B: per-wave 64 rows x (12+1 pad) f4

    const int tid  = threadIdx.x;
    const int wv   = tid >> 6;
    const int lane = tid & 63;
    float4* buf = obuf[wv];

    const long long rowBase = (long long)blockIdx.x * 256 + (long long)wv * 64;

    // ---- coalesced x load + wave-private transpose ----
    const float4* x4 = reinterpret_cast<const float4*>(x);
    const long long xMax = (long long)B * 6 - 1;           // last valid f4 index
    #pragma unroll
    for (int k = 0; k < 6; ++k) {
        const int lo = lane + 64 * k;                      // 0..383 local f4
        long long g = rowBase * 6 + lo;
        if (g > xMax) g = xMax;                            // tail clamp (never stored)
        const float4 v = x4[g];
        const int r = lo / 6, s = lo - 6 * r;
        buf[r * 13 + s] = v;
    }
    float xv[NJ];
    #pragma unroll
    for (int s = 0; s < 6; ++s) {
        const float4 v = buf[lane * 13 + s];
        xv[4*s+0] = v.x; xv[4*s+1] = v.y; xv[4*s+2] = v.z; xv[4*s+3] = v.w;
    }

    float feat[NJ][FEATN];                 // compile-time indices -> registers
    float4* out4 = reinterpret_cast<float4*>(out);

    constexpr int parents[NJ] = {-1,0,0,0,1,2,3,4,5,6,7,8,9,9,9,12,13,14,16,17,18,19,20,21};

    #pragma unroll
    for (int j = 0; j < NJ; ++j) {
        const float* W1j = W1 + j * (HIDN * HIDN);
        const float* b1j = b1 + j * HIDN;
        const float* W2j = W2 + j * (FEATN * HIDN);
        const float* b2j = b2 + j * FEATN;

        float inp[HIDN];
        inp[0] = xv[j];
        const int p = parents[j];
        #pragma unroll
        for (int c = 0; c < FEATN; ++c)
            inp[1 + c] = (p < 0) ? 0.f : feat[p][c];

        float h[HIDN];
        #pragma unroll
        for (int r = 0; r < HIDN; ++r) {
            float acc = b1j[r];
            #pragma unroll
            for (int c = 0; c < HIDN; ++c)
                acc = fmaf(W1j[r * HIDN + c], inp[c], acc);
            h[r] = fmaxf(acc, 0.f);
        }
        #pragma unroll
        for (int r = 0; r < FEATN; ++r) {
            float acc = b2j[r];
            #pragma unroll
            for (int c = 0; c < HIDN; ++c)
                acc = fmaf(W2j[r * HIDN + c], h[c], acc);
            feat[j][r] = fmaxf(acc, 0.f);
        }

        // ---- burst: LDS transpose + full-line global store ----
        if (j == 7 || j == 15 || j == 23) {
            const int b = j / 8;                           // 0,1,2 compile-time
            #pragma unroll
            for (int q = 0; q < 12; ++q) {                 // lane's 48 floats -> LDS
                float4 v;
                v.x = feat[b*8 + (4*q+0)/6][(4*q+0)%6];
                v.y = feat[b*8 + (4*q+1)/6][(4*q+1)%6];
                v.z = feat[b*8 + (4*q+2)/6][(4*q+2)%6];
                v.w = feat[b*8 + (4*q+3)/6][(4*q+3)%6];
                buf[lane * 13 + q] = v;
            }
            #pragma unroll
            for (int k = 0; k < 12; ++k) {                 // wave stores 12288 B
                const int o  = lane + 64 * k;              // 0..767
                const int rr = o / 12, s = o - 12 * rr;
                if (rowBase + rr < (long long)B)
                    out4[(rowBase + rr) * 36 + b * 12 + s] = buf[rr * 13 + s];
            }
        }
    }
}

extern "C" void kernel_launch(void* const* d_in, const int* in_sizes, int n_in,
                              void* d_out, int out_size, void* d_ws, size_t ws_size,
                              hipStream_t stream) {
    const float* x  = (const float*)d_in[0];
    const float* W1 = (const float*)d_in[1];
    const float* b1 = (const float*)d_in[2];
    const float* W2 = (const float*)d_in[3];
    const float* b2 = (const float*)d_in[4];
    float* out = (float*)d_out;

    const int B = in_sizes[0] / NJ;
    const int block = 256;
    const int grid = (B + block - 1) / block;
    // Launched TWICE (idempotent): dur2 - 409.4us(R5, same kernel once) = K.
    structure_encoder_kernel<<<grid, block, 0, stream>>>(x, W1, b1, W2, b2, out, B);
    structure_encoder_kernel<<<grid, block, 0, stream>>>(x, W1, b1, W2, b2, out, B);
}